// Round 1
// baseline (10037.991 us; speedup 1.0000x reference)
//
#include <hip/hip_runtime.h>
#include <math.h>

#define BB   64
#define TENC 128
#define TDEC 64
#define DHH  1024
#define DVV  2048
#define NCHN 256
#define GG   8704   // 4*DV + 2*NCH

__device__ __forceinline__ float sigmoidf_(float x) { return 1.f / (1.f + expf(-x)); }

// -------- zero init of recurrent state --------
__global__ __launch_bounds__(256) void k_init(float* __restrict__ h, float* __restrict__ c) {
    int i = blockIdx.x * 256 + threadIdx.x;   // grid 512 covers 131072
    h[i] = 0.f;
    c[i] = 0.f;
}

// -------- P = enc(8192x1024) @ W1(1024x1024) + b1 --------
__global__ __launch_bounds__(256) void k_P(const float* __restrict__ enc,
                                           const float* __restrict__ W1,
                                           const float* __restrict__ b1,
                                           float* __restrict__ P) {
    __shared__ float As[32][68];
    __shared__ float Bs[32][68];
    int j0 = blockIdx.x * 64;
    int m0 = blockIdx.y * 64;
    int tid = threadIdx.x;
    int jg = tid & 15, bg = tid >> 4;
    float acc[4][4] = {};
    for (int k0 = 0; k0 < DHH; k0 += 32) {
#pragma unroll
        for (int p = 0; p < 8; ++p) {
            int r = p * 8 + (tid >> 5);
            int kk = tid & 31;
            As[kk][r] = enc[(size_t)(m0 + r) * DHH + k0 + kk];
        }
#pragma unroll
        for (int p = 0; p < 8; ++p) {
            int kk = p * 4 + (tid >> 6);
            int jl = tid & 63;
            Bs[kk][jl] = W1[(size_t)(k0 + kk) * DHH + j0 + jl];
        }
        __syncthreads();
#pragma unroll
        for (int kk = 0; kk < 32; ++kk) {
            float4 a = *(const float4*)&As[kk][bg * 4];
            float4 b = *(const float4*)&Bs[kk][jg * 4];
            float av[4] = {a.x, a.y, a.z, a.w};
            float bv[4] = {b.x, b.y, b.z, b.w};
#pragma unroll
            for (int i = 0; i < 4; ++i)
#pragma unroll
                for (int j = 0; j < 4; ++j) acc[i][j] += av[i] * bv[j];
        }
        __syncthreads();
    }
    float4 bb = *(const float4*)&b1[j0 + jg * 4];
    float bia[4] = {bb.x, bb.y, bb.z, bb.w};
#pragma unroll
    for (int i = 0; i < 4; ++i) {
        int r = m0 + bg * 4 + i;
        float4 v = make_float4(acc[i][0] + bia[0], acc[i][1] + bia[1],
                               acc[i][2] + bia[2], acc[i][3] + bia[3]);
        *(float4*)&P[(size_t)r * DHH + j0 + jg * 4] = v;
    }
}

// -------- skinny GEMM: part[kseg][64][N] = A[64, kseg-slice] @ B[kseg-slice, N]
// A = concat(A1 (64xK1), A2 (64xK2)); B = concat(B1 (K1xN), B2 (K2xN)) --------
template <int KS>
__global__ __launch_bounds__(256) void k_skinny(const float* __restrict__ A1,
                                                const float* __restrict__ A2,
                                                const float* __restrict__ B1,
                                                const float* __restrict__ B2,
                                                int K1, int K2, int N,
                                                float* __restrict__ part) {
    __shared__ float As[32][68];
    __shared__ float Bs[32][68];
    int j0 = blockIdx.x * 64;
    int kseg = blockIdx.y;
    int tid = threadIdx.x;
    int jg = tid & 15, bg = tid >> 4;
    float acc[4][4] = {};
    for (int k0 = kseg * KS; k0 < (kseg + 1) * KS; k0 += 32) {
#pragma unroll
        for (int p = 0; p < 8; ++p) {
            int r = p * 8 + (tid >> 5);
            int kk = tid & 31;
            int k = k0 + kk;
            As[kk][r] = (k < K1) ? A1[r * K1 + k] : A2[r * K2 + (k - K1)];
        }
#pragma unroll
        for (int p = 0; p < 8; ++p) {
            int kk = p * 4 + (tid >> 6);
            int jl = tid & 63;
            int k = k0 + kk;
            Bs[kk][jl] = (k < K1) ? B1[(size_t)k * N + j0 + jl]
                                  : B2[(size_t)(k - K1) * N + j0 + jl];
        }
        __syncthreads();
#pragma unroll
        for (int kk = 0; kk < 32; ++kk) {
            float4 a = *(const float4*)&As[kk][bg * 4];
            float4 b = *(const float4*)&Bs[kk][jg * 4];
            float av[4] = {a.x, a.y, a.z, a.w};
            float bv[4] = {b.x, b.y, b.z, b.w};
#pragma unroll
            for (int i = 0; i < 4; ++i)
#pragma unroll
                for (int j = 0; j < 4; ++j) acc[i][j] += av[i] * bv[j];
        }
        __syncthreads();
    }
#pragma unroll
    for (int i = 0; i < 4; ++i) {
        int r = bg * 4 + i;
        float4 v = make_float4(acc[i][0], acc[i][1], acc[i][2], acc[i][3]);
        *(float4*)&part[(size_t)(kseg * 64 + r) * N + j0 + jg * 4] = v;
    }
}

// -------- e[b,t] = sum_d tanh(P[b,t,d] + hW[b,d]) * w2[d]  (also reduces hW partials)
__global__ __launch_bounds__(256) void k_e(const float* __restrict__ P,
                                           const float* __restrict__ hWp,
                                           const float* __restrict__ w2,
                                           float* __restrict__ e) {
    int b = blockIdx.x, tg = blockIdx.y;
    __shared__ float hw[DHH];
    __shared__ float w2s[DHH];
    int tid = threadIdx.x;
#pragma unroll
    for (int p = 0; p < 4; ++p) {
        int d = p * 256 + tid;
        float s = 0.f;
#pragma unroll
        for (int ks = 0; ks < 8; ++ks) s += hWp[(ks * 64 + b) * DHH + d];
        hw[d] = s;
        w2s[d] = w2[d];
    }
    __syncthreads();
    int wave = tid >> 6, lane = tid & 63;
    const float* Pb = P + (size_t)b * TENC * DHH;
    for (int tt = 0; tt < 8; ++tt) {
        int t = tg * 32 + wave * 8 + tt;
        const float* Pr = Pb + (size_t)t * DHH;
        float s = 0.f;
#pragma unroll
        for (int i = 0; i < 16; ++i) {
            int d = i * 64 + lane;
            s += tanhf(Pr[d] + hw[d]) * w2s[d];
        }
#pragma unroll
        for (int off = 32; off > 0; off >>= 1) s += __shfl_down(s, off);
        if (lane == 0) e[b * TENC + t] = s;
    }
}

// -------- softmax over t + context[b, dg*256+tid] --------
__global__ __launch_bounds__(256) void k_sc(const float* __restrict__ e,
                                            const float* __restrict__ enc,
                                            float* __restrict__ ctx) {
    int b = blockIdx.x, dg = blockIdx.y;
    __shared__ float al[TENC];
    __shared__ float red[256];
    int tid = threadIdx.x;
    float v = (tid < TENC) ? e[b * TENC + tid] : -3.0e38f;
    red[tid] = v;
    __syncthreads();
    for (int s = 128; s > 0; s >>= 1) {
        if (tid < s) red[tid] = fmaxf(red[tid], red[tid + s]);
        __syncthreads();
    }
    float mx = red[0];
    __syncthreads();
    float ex = (tid < TENC) ? expf(v - mx) : 0.f;
    red[tid] = ex;
    __syncthreads();
    for (int s = 128; s > 0; s >>= 1) {
        if (tid < s) red[tid] += red[tid + s];
        __syncthreads();
    }
    float inv = 1.f / red[0];
    if (tid < TENC) al[tid] = ex * inv;
    __syncthreads();
    int d = dg * 256 + tid;
    const float* ep = enc + (size_t)b * TENC * DHH + d;
    float acc = 0.f;
#pragma unroll 4
    for (int t = 0; t < TENC; ++t) acc += al[t] * ep[(size_t)t * DHH];
    ctx[b * DHH + d] = acc;
}

// -------- reduce gate partials + biases, cumsoftmax, ON-LSTM state update --------
__global__ __launch_bounds__(256) void k_pw(const float* __restrict__ part,
                                            const float* __restrict__ bih,
                                            const float* __restrict__ bhh,
                                            float* __restrict__ h,
                                            float* __restrict__ c,
                                            float* __restrict__ out, int t) {
    int b = blockIdx.x;
    __shared__ float g[GG];
    __shared__ float cs1[NCHN], cs2[NCHN], t1[NCHN], t2[NCHN];
    int tid = threadIdx.x;
    for (int p = 0; p < 34; ++p) {
        int j = p * 256 + tid;
        float s = bih[j] + bhh[j];
#pragma unroll
        for (int ks = 0; ks < 6; ++ks) s += part[(size_t)(ks * 64 + b) * GG + j];
        g[j] = s;
    }
    __syncthreads();
    float x1 = g[tid], x2 = g[NCHN + tid];
    t1[tid] = x1; t2[tid] = x2;
    __syncthreads();
    for (int s = 128; s > 0; s >>= 1) {
        if (tid < s) { t1[tid] = fmaxf(t1[tid], t1[tid + s]); t2[tid] = fmaxf(t2[tid], t2[tid + s]); }
        __syncthreads();
    }
    float m1 = t1[0], m2 = t2[0];
    __syncthreads();
    float e1 = expf(x1 - m1), e2 = expf(x2 - m2);
    t1[tid] = e1; t2[tid] = e2;
    __syncthreads();
    for (int s = 128; s > 0; s >>= 1) {
        if (tid < s) { t1[tid] += t1[tid + s]; t2[tid] += t2[tid + s]; }
        __syncthreads();
    }
    float inv1 = 1.f / t1[0], inv2 = 1.f / t2[0];
    __syncthreads();
    cs1[tid] = e1; cs2[tid] = e2;
    __syncthreads();
    for (int off = 1; off < NCHN; off <<= 1) {
        float a1 = (tid >= off) ? cs1[tid - off] : 0.f;
        float a2 = (tid >= off) ? cs2[tid - off] : 0.f;
        __syncthreads();
        cs1[tid] += a1; cs2[tid] += a2;
        __syncthreads();
    }
    float* cb = c + (size_t)b * DVV;
    float* hb = h + (size_t)b * DVV;
    float* ob = out + ((size_t)b * TDEC + t) * DVV;
    for (int p = 0; p < 8; ++p) {
        int idx = p * 256 + tid;
        int ch = idx >> 3;
        float cin = 1.f - cs1[ch] * inv1;
        float cfg = cs2[ch] * inv2;
        float ov = cfg * cin;
        float oo = sigmoidf_(g[512 + idx]);
        float gg = tanhf(g[2560 + idx]);
        float ii = sigmoidf_(g[4608 + idx]);
        float ff = sigmoidf_(g[6656 + idx]);
        float fg = ff * ov + (cfg - ov);
        float ig = ii * ov + (cin - ov);
        float cy = fg * cb[idx] + ig * gg;
        cb[idx] = cy;
        float hy = oo * tanhf(cy);
        hb[idx] = hy;
        ob[idx] = hy;
    }
}

extern "C" void kernel_launch(void* const* d_in, const int* in_sizes, int n_in,
                              void* d_out, int out_size, void* d_ws, size_t ws_size,
                              hipStream_t stream) {
    const float* enc    = (const float*)d_in[0];
    const float* W_att1 = (const float*)d_in[2];
    const float* b_att1 = (const float*)d_in[3];
    const float* w_att2 = (const float*)d_in[4];
    const float* W_ih   = (const float*)d_in[5];
    const float* b_ih   = (const float*)d_in[6];
    const float* W_hh   = (const float*)d_in[7];
    const float* b_hh   = (const float*)d_in[8];
    float* out = (float*)d_out;
    float* ws  = (float*)d_ws;

    float* P    = ws;                 // 8192*1024        = 8388608
    float* hWp  = P + 8388608;        // 8*64*1024        = 524288
    float* ebuf = hWp + 524288;       // 64*128           = 8192
    float* ctx  = ebuf + 8192;        // 64*1024          = 65536
    float* gp   = ctx + 65536;        // 6*64*8704        = 3342336
    float* h    = gp + 3342336;       // 64*2048          = 131072
    float* c    = h + 131072;         // 64*2048          = 131072
    if (ws_size < 12591104ull * 4ull) return;  // need ~48 MB scratch

    k_init<<<512, 256, 0, stream>>>(h, c);
    k_P<<<dim3(16, 128), 256, 0, stream>>>(enc, W_att1, b_att1, P);

    const float* Wh_att = W_att1 + 1024 * 1024;  // rows DH..DH+DV-1 of W_att1
    for (int t = 0; t < TDEC; ++t) {
        // hW = h @ W_att1[DH:]  (64x1024, K=2048), ksplit 8
        k_skinny<256><<<dim3(16, 8), 256, 0, stream>>>(h, h, Wh_att, Wh_att,
                                                       2048, 2048, DHH, hWp);
        // attention logits
        k_e<<<dim3(BB, 4), 256, 0, stream>>>(P, hWp, w_att2, ebuf);
        // softmax + context
        k_sc<<<dim3(BB, 4), 256, 0, stream>>>(ebuf, enc, ctx);
        // gates = [ctx|h] @ [W_ih; W_hh]  (64x8704, K=3072), ksplit 6
        k_skinny<512><<<dim3(136, 6), 256, 0, stream>>>(ctx, h, W_ih, W_hh,
                                                        1024, 2048, GG, gp);
        // reduce + biases + cumsoftmax + ON-LSTM update, write out[:, t, :]
        k_pw<<<BB, 256, 0, stream>>>(gp, b_ih, b_hh, h, c, out, t);
    }
}